// Round 1
// baseline (6467.648 us; speedup 1.0000x reference)
//
#include <hip/hip_runtime.h>

#define NAGENT 64
#define HID    128
#define EMB    64
#define TOBS   8
#define PREDL  12
#define NTHR   1024

__device__ __forceinline__ float sigm(float x) { return 1.0f / (1.0f + __expf(-x)); }

// One block per scene of 64 agents. 16 waves:
//  - sh_hT[k][agent] : transposed hidden state (conflict-free [k][lane] reads)
//  - c kept in registers: wave w owns hidden dims d = w*8 .. w*8+7 for all 64 agents
//  - social pooling via S[(e,g)][j] = soc_W[e,g,:] . h[j,:]  (dense GEMM), then
//    at[i,e] = soc_b[e] + sum_j pair_ij * S[e*4+gid_ij][j]   (masked gather)
__global__ __launch_bounds__(NTHR) void social_lstm_kernel(
    const float* __restrict__ past_traj,      // [1024][8][2]
    const float* __restrict__ past_traj_rel,  // [1024][8][2]
    const int*   __restrict__ ts_mask,        // [1024][8]
    const int*   __restrict__ scene_in,       // [1024]
    const float* __restrict__ pos_W,          // [64][2]
    const float* __restrict__ pos_b,          // [64]
    const float* __restrict__ soc_W,          // [64][512]
    const float* __restrict__ soc_b,          // [64]
    const float* __restrict__ Wih,            // [512][128]
    const float* __restrict__ Whh,            // [512][128]
    const float* __restrict__ bih,            // [512]
    const float* __restrict__ bhh,            // [512]
    const float* __restrict__ h0,             // [128]
    const float* __restrict__ c0,             // [128]
    const float* __restrict__ pred_W,         // [5][128]
    const float* __restrict__ pred_b,         // [5]
    float* __restrict__ out)                  // [61440 pred_out | 24576 pred_traj]
{
    __shared__ float sh_hT[HID][NAGENT];          // 32 KiB
    __shared__ float sh_xT[HID][NAGENT];          // 32 KiB  (rows 0..63 = et, 64..127 = at)
    __shared__ float sh_S[NAGENT][265];           // 67.8 KiB, S[j][row], pad 265 (9 mod 32, coprime)
    __shared__ signed char sh_tbl[NAGENT][NAGENT];// 4 KiB, tbl[j][i] = gid or -1
    __shared__ float sh_px[NAGENT], sh_py[NAGENT], sh_rx[NAGENT], sh_ry[NAGENT];
    __shared__ float sh_o[5][NAGENT];
    __shared__ int   sh_act[NAGENT];
    __shared__ int   sh_scene[NAGENT];

    const int tid   = threadIdx.x;
    const int lane  = tid & 63;
    const int wv    = __builtin_amdgcn_readfirstlane(tid >> 6); // wave id 0..15 (SGPR)
    const int gbase = blockIdx.x * NAGENT;

    // --- init: h broadcast from h0, c from c0; wave wv owns dims d0..d0+7 ---
    float c_reg[8], h_reg[8];
    const int d0 = wv * 8;
    #pragma unroll
    for (int r = 0; r < 8; ++r) {
        h_reg[r] = h0[d0 + r];
        c_reg[r] = c0[d0 + r];
        sh_hT[d0 + r][lane] = h_reg[r];
    }
    if (tid < NAGENT) sh_scene[tid] = scene_in[gbase + tid];
    __syncthreads();

    for (int step = 0; step < TOBS + PREDL; ++step) {
        if (step < TOBS) {
            // ---- obs step: load positions / rels / active mask ----
            if (tid < NAGENT) {
                const int ig = gbase + tid;
                sh_px[tid] = past_traj[(ig * TOBS + step) * 2 + 0];
                sh_py[tid] = past_traj[(ig * TOBS + step) * 2 + 1];
                sh_rx[tid] = past_traj_rel[(ig * TOBS + step) * 2 + 0];
                sh_ry[tid] = past_traj_rel[(ig * TOBS + step) * 2 + 1];
                sh_act[tid] = (ts_mask[ig * TOBS + step] == 1) ? 1 : 0;
            }
            // note: at step==TOBS-1 this also leaves sh_act = pred_active and
            // sh_px/py = past_traj[:, -1]  (exactly what the pred phase needs)
        } else {
            // ---- pred step: out = ht @ pred_W.T + pred_b (uses ht BEFORE update) ----
            if (tid < 5 * NAGENT) {
                const int q = wv; // 0..4
                float acc = pred_b[q];
                for (int d = 0; d < HID; ++d)
                    acc += sh_hT[d][lane] * pred_W[q * HID + d];
                sh_o[q][lane] = acc;
            }
            __syncthreads();
            if (tid < NAGENT) {
                const int i = tid;
                const float rx = sh_o[0][i], ry = sh_o[1][i];
                const float px = sh_px[i] + rx, py = sh_py[i] + ry; // pos += rel (unconditional, per ref)
                sh_px[i] = px; sh_py[i] = py;
                sh_rx[i] = rx; sh_ry[i] = ry;
                const float m = sh_act[i] ? 1.0f : 0.0f;           // pred_active mask
                const int p  = step - TOBS;
                const int ig = gbase + i;
                float* po = out + (ig * PREDL + p) * 5;
                #pragma unroll
                for (int q = 0; q < 5; ++q) po[q] = m * sh_o[q][i];
                float* pt = out + 61440 + (ig * PREDL + p) * 2;
                pt[0] = m * px;
                pt[1] = m * py;
            }
        }
        __syncthreads();

        // ---- Phase A: pair table tbl[j][i] = gid (0..3) if pair else -1 ----
        for (int p = tid; p < NAGENT * NAGENT; p += NTHR) {
            const int j = p >> 6, i = p & 63;
            const float dx = sh_px[j] - sh_px[i];   // rel = pos[j] - pos[i]
            const float dy = sh_py[j] - sh_py[i];
            const bool within = (dx < 0.99f) & (dx > -0.99f) & (dy < 0.99f) & (dy > -0.99f);
            const bool pair = within && (i != j) && (sh_scene[i] == sh_scene[j])
                              && sh_act[i] && sh_act[j];
            int gid = (int)floorf(dx + 1.0f) * 2 + (int)floorf(dy + 1.0f);
            gid = min(max(gid, 0), 3);
            sh_tbl[j][i] = pair ? (signed char)gid : (signed char)-1;
        }
        __syncthreads();

        // ---- Phase B: S[j][row] = sum_k soc_W[e, g*128+k] * h[j][k], row = e*4+g ----
        {
            const int row0 = wv * 16;            // 16 rows per wave, lane = j
            float acc[16];
            #pragma unroll
            for (int u = 0; u < 16; ++u) acc[u] = 0.0f;
            for (int k = 0; k < HID; ++k) {
                const float hk = sh_hT[k][lane];
                #pragma unroll
                for (int u = 0; u < 16; ++u) {
                    const int row = row0 + u;
                    acc[u] += soc_W[((row >> 2) << 9) + ((row & 3) << 7) + k] * hk;
                }
            }
            #pragma unroll
            for (int u = 0; u < 16; ++u) sh_S[lane][row0 + u] = acc[u];
        }
        __syncthreads();

        // ---- Phase C: at = relu(soc_b + gather(S)), et = relu(rel@pos_W.T + pos_b) ----
        {
            const int e0 = wv * 4;               // 4 embed dims per wave, lane = i
            float a0 = soc_b[e0], a1 = soc_b[e0 + 1], a2 = soc_b[e0 + 2], a3 = soc_b[e0 + 3];
            for (int j = 0; j < NAGENT; ++j) {
                const int v = (int)sh_tbl[j][lane];
                if (v >= 0) {
                    const float* Sp = &sh_S[j][v];
                    a0 += Sp[e0 * 4];
                    a1 += Sp[e0 * 4 + 4];
                    a2 += Sp[e0 * 4 + 8];
                    a3 += Sp[e0 * 4 + 12];
                }
            }
            sh_xT[EMB + e0    ][lane] = fmaxf(a0, 0.0f);
            sh_xT[EMB + e0 + 1][lane] = fmaxf(a1, 0.0f);
            sh_xT[EMB + e0 + 2][lane] = fmaxf(a2, 0.0f);
            sh_xT[EMB + e0 + 3][lane] = fmaxf(a3, 0.0f);
            const float rx = sh_rx[lane], ry = sh_ry[lane];
            #pragma unroll
            for (int u = 0; u < 4; ++u) {
                const int e = e0 + u;
                sh_xT[e][lane] = fmaxf(pos_b[e] + rx * pos_W[e * 2] + ry * pos_W[e * 2 + 1], 0.0f);
            }
        }
        __syncthreads();

        // ---- Phase D: LSTM gates (wave wv -> dims d0..d0+7, lane = agent) ----
        {
            float zi[8], zf[8], zg[8], zo[8];
            #pragma unroll
            for (int r = 0; r < 8; ++r) {
                const int d = d0 + r;
                zi[r] = bih[d]       + bhh[d];
                zf[r] = bih[128 + d] + bhh[128 + d];
                zg[r] = bih[256 + d] + bhh[256 + d];
                zo[r] = bih[384 + d] + bhh[384 + d];
            }
            for (int k = 0; k < HID; ++k) {
                const float xk = sh_xT[k][lane];
                const float hk = sh_hT[k][lane];
                #pragma unroll
                for (int r = 0; r < 8; ++r) {
                    const int d = d0 + r;
                    zi[r] += Wih[d * HID + k] * xk         + Whh[d * HID + k] * hk;
                    zf[r] += Wih[(128 + d) * HID + k] * xk + Whh[(128 + d) * HID + k] * hk;
                    zg[r] += Wih[(256 + d) * HID + k] * xk + Whh[(256 + d) * HID + k] * hk;
                    zo[r] += Wih[(384 + d) * HID + k] * xk + Whh[(384 + d) * HID + k] * hk;
                }
            }
            const int act = sh_act[lane];
            __syncthreads();   // all waves done READING sh_hT before we overwrite it
            #pragma unroll
            for (int r = 0; r < 8; ++r) {
                const float cn = sigm(zf[r]) * c_reg[r] + sigm(zi[r]) * tanhf(zg[r]);
                const float hn = sigm(zo[r]) * tanhf(cn);
                if (act) { c_reg[r] = cn; h_reg[r] = hn; }
                sh_hT[d0 + r][lane] = h_reg[r];
            }
        }
        __syncthreads();
    }
}

extern "C" void kernel_launch(void* const* d_in, const int* in_sizes, int n_in,
                              void* d_out, int out_size, void* d_ws, size_t ws_size,
                              hipStream_t stream) {
    (void)in_sizes; (void)n_in; (void)d_ws; (void)ws_size; (void)out_size;
    social_lstm_kernel<<<16, NTHR, 0, stream>>>(
        (const float*)d_in[0],   // past_traj
        (const float*)d_in[1],   // past_traj_rel
        (const int*)  d_in[2],   // past_traj_timestamp_mask
        (const int*)  d_in[4],   // same_scene_mask  (d_in[3] is_predictable: unused by ref)
        (const float*)d_in[5],   // pos_W
        (const float*)d_in[6],   // pos_b
        (const float*)d_in[7],   // soc_W
        (const float*)d_in[8],   // soc_b
        (const float*)d_in[9],   // Wih
        (const float*)d_in[10],  // Whh
        (const float*)d_in[11],  // bih
        (const float*)d_in[12],  // bhh
        (const float*)d_in[13],  // h0
        (const float*)d_in[14],  // c0
        (const float*)d_in[15],  // pred_W
        (const float*)d_in[16],  // pred_b
        (float*)d_out);
}

// Round 2
// 418.843 us; speedup vs baseline: 15.4417x; 15.4417x over previous
//
#include <hip/hip_runtime.h>

#define NAGENT 64
#define HID    128
#define TOBS   8
#define PREDL  12
#define NTHR   1024
#define XP     264           // sh_X row pitch in ushorts (256 + 8 pad -> 528B, 16B-aligned)
#define SP     65            // sh_S row pitch in floats

typedef __attribute__((ext_vector_type(8))) short bf16x8;
typedef __attribute__((ext_vector_type(4))) float f32x4;

__device__ __forceinline__ unsigned short f2bf(float f) {
    unsigned int x = __float_as_uint(f);
    unsigned int r = (x + 0x7fffu + ((x >> 16) & 1u)) >> 16;   // RNE
    return (unsigned short)r;
}
__device__ __forceinline__ float bf2f(unsigned short u) {
    return __uint_as_float(((unsigned int)u) << 16);
}
__device__ __forceinline__ float sigmf(float x) {
    return __builtin_amdgcn_rcpf(1.0f + __expf(-x));
}
__device__ __forceinline__ float tanhf_fast(float x) {
    x = fminf(fmaxf(x, -15.0f), 15.0f);
    float e = __expf(2.0f * x);
    return (e - 1.0f) * __builtin_amdgcn_rcpf(e + 1.0f);
}
__device__ __forceinline__ float sel4(float a0, float a1, float a2, float a3, int k) {
    float lo = (k & 1) ? a1 : a0;
    float hi = (k & 1) ? a3 : a2;
    return (k & 2) ? hi : lo;
}

// ---------------- prep: pack weights into bf16 MFMA B-fragment layout ----------------
// WD (phase D): B[k][n], k=0..255 ([x|h]), n=0..511 gate-interleaved n=d*4+g.
//   frag idx = ((nt*8+kt)*64 + l)*8 + e ; k = kt*32+(l>>4)*8+e ; n = nt*16+(l&15)
// WB (phase B): B2[k][r], k=0..127 (h), r=0..255, r = e*4+g.
__global__ void prep_weights(const float* __restrict__ Wih, const float* __restrict__ Whh,
                             const float* __restrict__ socW,
                             unsigned short* __restrict__ wd, unsigned short* __restrict__ wb) {
    int idx = blockIdx.x * blockDim.x + threadIdx.x;
    if (idx < 131072) {
        int e = idx & 7, l = (idx >> 3) & 63, t = idx >> 9;   // t = nt*8+kt
        int kt = t & 7, nt = t >> 3;
        int k = kt * 32 + ((l >> 4) << 3) + e;
        int n = nt * 16 + (l & 15);
        int d = n >> 2, g = n & 3;
        int row = g * 128 + d;
        float v = (k < 128) ? Wih[row * 128 + k] : Whh[row * 128 + (k - 128)];
        wd[idx] = f2bf(v);
    } else if (idx < 163840) {
        int idx2 = idx - 131072;
        int e = idx2 & 7, l = (idx2 >> 3) & 63, t = idx2 >> 9; // t = nt*4+kt
        int kt = t & 3, nt = t >> 2;
        int k = kt * 32 + ((l >> 4) << 3) + e;
        int r = nt * 16 + (l & 15);
        int eo = r >> 2, g = r & 3;
        wb[idx2] = f2bf(socW[eo * 512 + g * 128 + k]);
    }
}

// ---------------- main: one block per 64-agent scene, 16 waves ----------------
__global__ __launch_bounds__(NTHR) void social_lstm_mfma(
    const float* __restrict__ past_traj, const float* __restrict__ past_traj_rel,
    const int* __restrict__ ts_mask, const int* __restrict__ scene_in,
    const float* __restrict__ pos_W, const float* __restrict__ pos_b,
    const float* __restrict__ soc_b,
    const float* __restrict__ bih, const float* __restrict__ bhh,
    const float* __restrict__ h0, const float* __restrict__ c0,
    const float* __restrict__ pred_W, const float* __restrict__ pred_b,
    const unsigned short* __restrict__ wd, const unsigned short* __restrict__ wb,
    float* __restrict__ out)
{
    __shared__ __align__(16) unsigned short sh_X[NAGENT][XP]; // cols 0..63 et | 64..127 at | 128..255 h (bf16)
    __shared__ float sh_S[256][SP];
    __shared__ signed char sh_tbl[NAGENT][NAGENT];
    __shared__ float sh_px[NAGENT], sh_py[NAGENT], sh_rx[NAGENT], sh_ry[NAGENT];
    __shared__ float sh_o[5][NAGENT];
    __shared__ int   sh_act[NAGENT], sh_scene[NAGENT];

    const int tid  = threadIdx.x;
    const int lane = tid & 63;
    const int wv   = __builtin_amdgcn_readfirstlane(tid >> 6);  // 0..15
    const int gbase = blockIdx.x * NAGENT;
    const int c16 = lane & 15;   // tile col
    const int q4  = lane >> 4;   // quad
    const int go  = c16 & 3;     // owned gate (i,f,g,o)
    const int dq  = c16 >> 2;    // dim-within-ntile

    // per-wave geometry: phase D N-tiles 2wv, 2wv+1
    float bs[2], c_st[4][2], hnew[4][2];
    int dimv[2];
    #pragma unroll
    for (int s = 0; s < 2; ++s) {
        const int n = (2 * wv + s) * 16 + c16;  // column 0..511 (= dim*4+gate)
        const int d = n >> 2, g = n & 3;
        bs[s] = bih[g * 128 + d] + bhh[g * 128 + d];
        dimv[s] = (2 * wv + s) * 4 + dq;
        #pragma unroll
        for (int mj = 0; mj < 4; ++mj) c_st[mj][s] = c0[dimv[s]];
    }
    for (int p = tid; p < NAGENT * HID; p += NTHR) {
        int a = p >> 7, d = p & 127;
        sh_X[a][128 + d] = f2bf(h0[d]);
    }
    if (tid < NAGENT) sh_scene[tid] = scene_in[gbase + tid];
    __syncthreads();

    const bf16x8* wdp = (const bf16x8*)wd + (2 * wv * 8) * 64 + lane;  // +kt*64, +512 for ntile+1
    const bf16x8* wbp = (const bf16x8*)wb + (wv * 4) * 64 + lane;      // +kt*64
    const unsigned short* xaD = &sh_X[c16][q4 * 8];        // A-frag base, phase D (k 0..255)
    const unsigned short* xaB = &sh_X[c16][128 + q4 * 8];  // A-frag base, phase B (h region)

    for (int step = 0; step < TOBS + PREDL; ++step) {
        if (step < TOBS) {
            if (tid < NAGENT) {
                const int ig = gbase + tid;
                sh_px[tid] = past_traj[(ig * TOBS + step) * 2 + 0];
                sh_py[tid] = past_traj[(ig * TOBS + step) * 2 + 1];
                sh_rx[tid] = past_traj_rel[(ig * TOBS + step) * 2 + 0];
                sh_ry[tid] = past_traj_rel[(ig * TOBS + step) * 2 + 1];
                sh_act[tid] = (ts_mask[ig * TOBS + step] == 1) ? 1 : 0;
            }
        } else {
            // pred projection: out = ht @ pred_W.T + pred_b (ht from bf16 h in LDS)
            if (tid < 5 * NAGENT) {
                float acc = pred_b[wv];
                for (int d = 0; d < HID; ++d)
                    acc += bf2f(sh_X[lane][128 + d]) * pred_W[wv * HID + d];
                sh_o[wv][lane] = acc;
            }
            __syncthreads();
            if (tid < NAGENT) {
                const int i = tid;
                const float rx = sh_o[0][i], ry = sh_o[1][i];
                const float px = sh_px[i] + rx, py = sh_py[i] + ry;
                sh_px[i] = px; sh_py[i] = py;
                sh_rx[i] = rx; sh_ry[i] = ry;
                const float m = sh_act[i] ? 1.0f : 0.0f;
                const int p = step - TOBS;
                const int ig = gbase + i;
                float* po = out + (ig * PREDL + p) * 5;
                #pragma unroll
                for (int q = 0; q < 5; ++q) po[q] = m * sh_o[q][i];
                float* pt = out + 61440 + (ig * PREDL + p) * 2;
                pt[0] = m * px; pt[1] = m * py;
            }
        }
        __syncthreads();

        // ---- Phase A: pair table ----
        for (int p = tid; p < NAGENT * NAGENT; p += NTHR) {
            const int j = p >> 6, i = p & 63;
            const float dx = sh_px[j] - sh_px[i];
            const float dy = sh_py[j] - sh_py[i];
            const bool within = (dx < 0.99f) & (dx > -0.99f) & (dy < 0.99f) & (dy > -0.99f);
            const bool pair = within && (i != j) && (sh_scene[i] == sh_scene[j])
                              && sh_act[i] && sh_act[j];
            int gid = (int)floorf(dx + 1.0f) * 2 + (int)floorf(dy + 1.0f);
            gid = min(max(gid, 0), 3);
            sh_tbl[j][i] = pair ? (signed char)gid : (signed char)-1;
        }
        __syncthreads();

        // ---- Phase B (MFMA): S[r][j] = sum_k h[j][k] * B2[k][r], wave = N-tile wv ----
        {
            f32x4 acc2[4];
            #pragma unroll
            for (int mj = 0; mj < 4; ++mj) acc2[mj] = (f32x4){0.f, 0.f, 0.f, 0.f};
            #pragma unroll
            for (int kt = 0; kt < 4; ++kt) {
                const bf16x8 b = wbp[kt * 64];
                #pragma unroll
                for (int mj = 0; mj < 4; ++mj) {
                    const bf16x8 a = *(const bf16x8*)(xaB + mj * 16 * XP + kt * 32);
                    acc2[mj] = __builtin_amdgcn_mfma_f32_16x16x32_bf16(a, b, acc2[mj], 0, 0, 0);
                }
            }
            #pragma unroll
            for (int mj = 0; mj < 4; ++mj)
                #pragma unroll
                for (int i = 0; i < 4; ++i)
                    sh_S[wv * 16 + c16][mj * 16 + q4 * 4 + i] = acc2[mj][i];
        }
        __syncthreads();

        // ---- Phase C: at = relu(soc_b + gather(S)); et = relu(rel@pos_W.T + pos_b) ----
        {
            const int e0 = wv * 4;
            float a0 = soc_b[e0], a1 = soc_b[e0 + 1], a2 = soc_b[e0 + 2], a3 = soc_b[e0 + 3];
            for (int j = 0; j < NAGENT; ++j) {
                const int v = (int)sh_tbl[j][lane];
                if (v >= 0) {
                    a0 += sh_S[e0 * 4 + v][j];
                    a1 += sh_S[e0 * 4 + 4 + v][j];
                    a2 += sh_S[e0 * 4 + 8 + v][j];
                    a3 += sh_S[e0 * 4 + 12 + v][j];
                }
            }
            sh_X[lane][64 + e0    ] = f2bf(fmaxf(a0, 0.f));
            sh_X[lane][64 + e0 + 1] = f2bf(fmaxf(a1, 0.f));
            sh_X[lane][64 + e0 + 2] = f2bf(fmaxf(a2, 0.f));
            sh_X[lane][64 + e0 + 3] = f2bf(fmaxf(a3, 0.f));
            const float rx = sh_rx[lane], ry = sh_ry[lane];
            #pragma unroll
            for (int u = 0; u < 4; ++u) {
                const int e = e0 + u;
                sh_X[lane][e] = f2bf(fmaxf(pos_b[e] + rx * pos_W[e * 2] + ry * pos_W[e * 2 + 1], 0.f));
            }
        }
        __syncthreads();

        // ---- Phase D (MFMA): Z = X @ WD^T ; wave owns N-tiles 2wv,2wv+1, all 4 M-tiles ----
        {
            f32x4 acc[4][2];
            #pragma unroll
            for (int mj = 0; mj < 4; ++mj) {
                acc[mj][0] = (f32x4){0.f, 0.f, 0.f, 0.f};
                acc[mj][1] = (f32x4){0.f, 0.f, 0.f, 0.f};
            }
            #pragma unroll 2
            for (int kt = 0; kt < 8; ++kt) {
                const bf16x8 b0 = wdp[kt * 64];
                const bf16x8 b1 = wdp[kt * 64 + 512];
                #pragma unroll
                for (int mj = 0; mj < 4; ++mj) {
                    const bf16x8 a = *(const bf16x8*)(xaD + mj * 16 * XP + kt * 32);
                    acc[mj][0] = __builtin_amdgcn_mfma_f32_16x16x32_bf16(a, b0, acc[mj][0], 0, 0, 0);
                    acc[mj][1] = __builtin_amdgcn_mfma_f32_16x16x32_bf16(a, b1, acc[mj][1], 0, 0, 0);
                }
            }
            // ---- pointwise LSTM: 4-lane gate exchange, lane owns agent-subrow i==go ----
            #pragma unroll
            for (int mj = 0; mj < 4; ++mj) {
                const int a = mj * 16 + q4 * 4 + go;
                const bool act = sh_act[a] != 0;
                #pragma unroll
                for (int s = 0; s < 2; ++s) {
                    const float z0 = acc[mj][s][0] + bs[s];
                    const float z1 = acc[mj][s][1] + bs[s];
                    const float z2 = acc[mj][s][2] + bs[s];
                    const float z3 = acc[mj][s][3] + bs[s];
                    const float s0 = sel4(z0, z1, z2, z3, go);
                    const float s1 = sel4(z0, z1, z2, z3, go ^ 1);
                    const float s2 = sel4(z0, z1, z2, z3, go ^ 2);
                    const float s3 = sel4(z0, z1, z2, z3, go ^ 3);
                    const float t1 = __shfl_xor(s1, 1, 64);
                    const float t2 = __shfl_xor(s2, 2, 64);
                    const float t3 = __shfl_xor(s3, 3, 64);
                    const float zi = sel4(s0, t1, t2, t3, go);
                    const float zf = sel4(s0, t1, t2, t3, go ^ 1);
                    const float zg = sel4(s0, t1, t2, t3, go ^ 2);
                    const float zo = sel4(s0, t1, t2, t3, go ^ 3);
                    const float cold = c_st[mj][s];
                    const float cn = sigmf(zf) * cold + sigmf(zi) * tanhf_fast(zg);
                    const float hn = sigmf(zo) * tanhf_fast(cn);
                    c_st[mj][s] = act ? cn : cold;
                    const float hold = bf2f(sh_X[a][128 + dimv[s]]);
                    hnew[mj][s] = act ? hn : hold;
                }
            }
        }
        __syncthreads();   // everyone done reading h region
        #pragma unroll
        for (int mj = 0; mj < 4; ++mj) {
            const int a = mj * 16 + q4 * 4 + go;
            sh_X[a][128 + dimv[0]] = f2bf(hnew[mj][0]);
            sh_X[a][128 + dimv[1]] = f2bf(hnew[mj][1]);
        }
        __syncthreads();
    }
}

extern "C" void kernel_launch(void* const* d_in, const int* in_sizes, int n_in,
                              void* d_out, int out_size, void* d_ws, size_t ws_size,
                              hipStream_t stream) {
    (void)in_sizes; (void)n_in; (void)out_size; (void)ws_size;
    unsigned short* wd = (unsigned short*)d_ws;            // 256 KiB
    unsigned short* wb = wd + 131072;                      //  64 KiB
    prep_weights<<<640, 256, 0, stream>>>(
        (const float*)d_in[9], (const float*)d_in[10], (const float*)d_in[7], wd, wb);
    social_lstm_mfma<<<16, NTHR, 0, stream>>>(
        (const float*)d_in[0],   // past_traj
        (const float*)d_in[1],   // past_traj_rel
        (const int*)  d_in[2],   // ts mask
        (const int*)  d_in[4],   // same_scene_mask
        (const float*)d_in[5],   // pos_W
        (const float*)d_in[6],   // pos_b
        (const float*)d_in[8],   // soc_b
        (const float*)d_in[11],  // bih
        (const float*)d_in[12],  // bhh
        (const float*)d_in[13],  // h0
        (const float*)d_in[14],  // c0
        (const float*)d_in[15],  // pred_W
        (const float*)d_in[16],  // pred_b
        wd, wb,
        (float*)d_out);
}

// Round 3
// 294.054 us; speedup vs baseline: 21.9948x; 1.4244x over previous
//
#include <hip/hip_runtime.h>

#define NAGENT 64
#define HID    128
#define TOBS   8
#define PREDL  12
#define NTHR   1024
#define XP     264           // sh_X row pitch (ushort): 256 + 8 pad, 16B-aligned rows
#define PP     264           // sh_P row pitch
#define S2P    264           // sh_S2 row pitch

typedef __attribute__((ext_vector_type(8))) short bf16x8;
typedef __attribute__((ext_vector_type(4))) short bf16x4;
typedef __attribute__((ext_vector_type(4))) float f32x4;

__device__ __forceinline__ unsigned short f2bf(float f) {
    unsigned int x = __float_as_uint(f);
    unsigned int r = (x + 0x7fffu + ((x >> 16) & 1u)) >> 16;   // RNE
    return (unsigned short)r;
}
__device__ __forceinline__ float bf2f(unsigned short u) {
    return __uint_as_float(((unsigned int)u) << 16);
}
__device__ __forceinline__ float sigmf(float x) {
    return __builtin_amdgcn_rcpf(1.0f + __expf(-x));
}
__device__ __forceinline__ float tanhf_fast(float x) {
    x = fminf(fmaxf(x, -15.0f), 15.0f);
    float e = __expf(2.0f * x);
    return (e - 1.0f) * __builtin_amdgcn_rcpf(e + 1.0f);
}
__device__ __forceinline__ float sel4(float a0, float a1, float a2, float a3, int k) {
    float lo = (k & 1) ? a1 : a0;
    float hi = (k & 1) ? a3 : a2;
    return (k & 2) ? hi : lo;
}

// ---------------- prep: pack weights into bf16 MFMA B-fragment layout ----------------
// WD (phase D): B[k][n], k=0..255 ([x|h]), n=0..511 gate-interleaved n=d*4+g.
//   frag idx = ((nt*8+kt)*64 + l)*8 + e ; k = kt*32+(l>>4)*8+e ; n = nt*16+(l&15)
// WB (phase B): B2[k][r], k=0..127 (h), r=0..255, r = e*4+g.
__global__ void prep_weights(const float* __restrict__ Wih, const float* __restrict__ Whh,
                             const float* __restrict__ socW,
                             unsigned short* __restrict__ wd, unsigned short* __restrict__ wb) {
    int idx = blockIdx.x * blockDim.x + threadIdx.x;
    if (idx < 131072) {
        int e = idx & 7, l = (idx >> 3) & 63, t = idx >> 9;   // t = nt*8+kt
        int kt = t & 7, nt = t >> 3;
        int k = kt * 32 + ((l >> 4) << 3) + e;
        int n = nt * 16 + (l & 15);
        int d = n >> 2, g = n & 3;
        int row = g * 128 + d;
        float v = (k < 128) ? Wih[row * 128 + k] : Whh[row * 128 + (k - 128)];
        wd[idx] = f2bf(v);
    } else if (idx < 163840) {
        int idx2 = idx - 131072;
        int e = idx2 & 7, l = (idx2 >> 3) & 63, t = idx2 >> 9; // t = nt*4+kt
        int kt = t & 3, nt = t >> 2;
        int k = kt * 32 + ((l >> 4) << 3) + e;
        int r = nt * 16 + (l & 15);
        int eo = r >> 2, g = r & 3;
        wb[idx2] = f2bf(socW[eo * 512 + g * 128 + k]);
    }
}

// ---------------- main: one block per 64-agent scene, 16 waves ----------------
__global__ __launch_bounds__(NTHR) void social_lstm_mfma(
    const float* __restrict__ past_traj, const float* __restrict__ past_traj_rel,
    const int* __restrict__ ts_mask, const int* __restrict__ scene_in,
    const float* __restrict__ pos_W, const float* __restrict__ pos_b,
    const float* __restrict__ soc_b,
    const float* __restrict__ bih, const float* __restrict__ bhh,
    const float* __restrict__ h0, const float* __restrict__ c0,
    const float* __restrict__ pred_W, const float* __restrict__ pred_b,
    const unsigned short* __restrict__ wd, const unsigned short* __restrict__ wb,
    float* __restrict__ out)
{
    __shared__ __align__(16) unsigned short sh_X[NAGENT][XP];  // 0..63 et | 64..127 at | 128..255 h
    __shared__ __align__(16) unsigned short sh_P[NAGENT][PP];  // P[i][k], k = g*64+j, bf16 0/1
    __shared__ __align__(16) unsigned short sh_S2[NAGENT][S2P];// S2[e][k], k = g*64+j, bf16
    __shared__ float sh_px[NAGENT], sh_py[NAGENT], sh_rx[NAGENT], sh_ry[NAGENT];
    __shared__ float sh_o[5][NAGENT];
    __shared__ int   sh_act[NAGENT], sh_scene[NAGENT];

    const int tid  = threadIdx.x;
    const int lane = tid & 63;
    const int wv   = __builtin_amdgcn_readfirstlane(tid >> 6);  // 0..15
    const int gbase = blockIdx.x * NAGENT;
    const int c16 = lane & 15;   // tile col
    const int q4  = lane >> 4;   // quad
    const int go  = c16 & 3;     // owned gate (i,f,g,o)
    const int dq  = c16 >> 2;    // dim-within-ntile

    // per-wave geometry: phase D N-tiles 2wv, 2wv+1
    float bs[2], c_st[4][2], hnew[4][2];
    int dimv[2];
    #pragma unroll
    for (int s = 0; s < 2; ++s) {
        const int n = (2 * wv + s) * 16 + c16;  // column 0..511 (= dim*4+gate)
        const int d = n >> 2, g = n & 3;
        bs[s] = bih[g * 128 + d] + bhh[g * 128 + d];
        dimv[s] = (2 * wv + s) * 4 + dq;
        #pragma unroll
        for (int mj = 0; mj < 4; ++mj) c_st[mj][s] = c0[dimv[s]];
    }
    for (int p = tid; p < NAGENT * HID; p += NTHR) {
        int a = p >> 7, d = p & 127;
        sh_X[a][128 + d] = f2bf(h0[d]);
    }
    if (tid < NAGENT) sh_scene[tid] = scene_in[gbase + tid];
    __syncthreads();

    const bf16x8* wdp = (const bf16x8*)wd + (2 * wv * 8) * 64 + lane;  // +kt*64, +512 for ntile+1
    const bf16x8* wbp = (const bf16x8*)wb + (wv * 4) * 64 + lane;      // +kt*64
    const unsigned short* xaD = &sh_X[c16][q4 * 8];        // A-frag base, phase D (k 0..255)
    const unsigned short* xaB = &sh_X[c16][128 + q4 * 8];  // A-frag base, phase B (h region)

    for (int step = 0; step < TOBS + PREDL; ++step) {
        if (step < TOBS) {
            if (tid < NAGENT) {
                const int ig = gbase + tid;
                sh_px[tid] = past_traj[(ig * TOBS + step) * 2 + 0];
                sh_py[tid] = past_traj[(ig * TOBS + step) * 2 + 1];
                sh_rx[tid] = past_traj_rel[(ig * TOBS + step) * 2 + 0];
                sh_ry[tid] = past_traj_rel[(ig * TOBS + step) * 2 + 1];
                sh_act[tid] = (ts_mask[ig * TOBS + step] == 1) ? 1 : 0;
            }
        } else {
            // pred projection: out = ht @ pred_W.T + pred_b (vectorized b128 LDS reads)
            if (tid < 5 * NAGENT) {
                float acc = pred_b[wv];
                const float* pw = pred_W + wv * HID;
                #pragma unroll
                for (int u = 0; u < 16; ++u) {
                    const bf16x8 v = *(const bf16x8*)&sh_X[lane][128 + u * 8];
                    #pragma unroll
                    for (int e = 0; e < 8; ++e)
                        acc += bf2f((unsigned short)v[e]) * pw[u * 8 + e];
                }
                sh_o[wv][lane] = acc;
            }
            __syncthreads();
            if (tid < NAGENT) {
                const int i = tid;
                const float rx = sh_o[0][i], ry = sh_o[1][i];
                const float px = sh_px[i] + rx, py = sh_py[i] + ry;
                sh_px[i] = px; sh_py[i] = py;
                sh_rx[i] = rx; sh_ry[i] = ry;
                const float m = sh_act[i] ? 1.0f : 0.0f;
                const int p = step - TOBS;
                const int ig = gbase + i;
                float* po = out + (ig * PREDL + p) * 5;
                #pragma unroll
                for (int q = 0; q < 5; ++q) po[q] = m * sh_o[q][i];
                float* pt = out + 61440 + (ig * PREDL + p) * 2;
                pt[0] = m * px; pt[1] = m * py;
            }
        }
        __syncthreads();

        // ==== Region 1: Phase A (P one-hot), et, Phase B (S2 = socW@h^T via MFMA) ====
        // ---- Phase A: P[i][g*64+j] = 1.0 if (pair_ij && gid==g) ----
        #pragma unroll
        for (int it = 0; it < 4; ++it) {
            const int p = (it << 10) + tid;
            const int i = p >> 6, j = p & 63;           // lanes vary j -> coalesced writes
            const float dx = sh_px[j] - sh_px[i];
            const float dy = sh_py[j] - sh_py[i];
            const bool within = (dx < 0.99f) & (dx > -0.99f) & (dy < 0.99f) & (dy > -0.99f);
            const bool pair = within && (i != j) && (sh_scene[i] == sh_scene[j])
                              && sh_act[i] && sh_act[j];
            int gid = (int)floorf(dx + 1.0f) * 2 + (int)floorf(dy + 1.0f);
            gid = min(max(gid, 0), 3);
            #pragma unroll
            for (int g = 0; g < 4; ++g)
                sh_P[i][g * 64 + j] = (pair && gid == g) ? (unsigned short)0x3f80
                                                         : (unsigned short)0;
        }
        // ---- et = relu(rel@pos_W.T + pos_b), wave wv -> embed dims wv*4.. ----
        {
            const float rx = sh_rx[lane], ry = sh_ry[lane];
            const int e0 = wv * 4;
            #pragma unroll
            for (int u = 0; u < 4; ++u) {
                const int e = e0 + u;
                sh_X[lane][e] = f2bf(fmaxf(pos_b[e] + rx * pos_W[e * 2] + ry * pos_W[e * 2 + 1], 0.f));
            }
        }
        // ---- Phase B (MFMA): S[r][j], r=wv*16+c16; store bf16 transposed to sh_S2[e][g*64+j] ----
        {
            f32x4 acc2[4];
            #pragma unroll
            for (int mj = 0; mj < 4; ++mj) acc2[mj] = (f32x4){0.f, 0.f, 0.f, 0.f};
            #pragma unroll
            for (int kt = 0; kt < 4; ++kt) {
                const bf16x8 b = wbp[kt * 64];
                #pragma unroll
                for (int mj = 0; mj < 4; ++mj) {
                    const bf16x8 a = *(const bf16x8*)(xaB + mj * 16 * XP + kt * 32);
                    acc2[mj] = __builtin_amdgcn_mfma_f32_16x16x32_bf16(a, b, acc2[mj], 0, 0, 0);
                }
            }
            const int r = wv * 16 + c16;
            unsigned short* dst = &sh_S2[r >> 2][(r & 3) * 64 + q4 * 4];
            #pragma unroll
            for (int mj = 0; mj < 4; ++mj) {
                bf16x4 pk;
                #pragma unroll
                for (int i = 0; i < 4; ++i) pk[i] = (short)f2bf(acc2[mj][i]);
                *(bf16x4*)(dst + mj * 16) = pk;
            }
        }
        __syncthreads();

        // ==== Region 2: Phase C2 (MFMA): at = relu(P @ S2 + soc_b) ====
        {
            const int mt = wv & 3, nt = wv >> 2;
            f32x4 acc = (f32x4){0.f, 0.f, 0.f, 0.f};
            const unsigned short* pa = &sh_P[mt * 16 + c16][q4 * 8];
            const unsigned short* pb = &sh_S2[nt * 16 + c16][q4 * 8];
            #pragma unroll
            for (int kt = 0; kt < 8; ++kt) {
                const bf16x8 a = *(const bf16x8*)(pa + kt * 32);
                const bf16x8 b = *(const bf16x8*)(pb + kt * 32);
                acc = __builtin_amdgcn_mfma_f32_16x16x32_bf16(a, b, acc, 0, 0, 0);
            }
            const int e_ = nt * 16 + c16;
            const float sb = soc_b[e_];
            #pragma unroll
            for (int rr = 0; rr < 4; ++rr)
                sh_X[mt * 16 + q4 * 4 + rr][64 + e_] = f2bf(fmaxf(acc[rr] + sb, 0.f));
        }
        __syncthreads();

        // ==== Region 3: Phase D (MFMA) Z = X @ WD^T + pointwise LSTM ====
        {
            f32x4 acc[4][2];
            #pragma unroll
            for (int mj = 0; mj < 4; ++mj) {
                acc[mj][0] = (f32x4){0.f, 0.f, 0.f, 0.f};
                acc[mj][1] = (f32x4){0.f, 0.f, 0.f, 0.f};
            }
            #pragma unroll 2
            for (int kt = 0; kt < 8; ++kt) {
                const bf16x8 b0 = wdp[kt * 64];
                const bf16x8 b1 = wdp[kt * 64 + 512];
                #pragma unroll
                for (int mj = 0; mj < 4; ++mj) {
                    const bf16x8 a = *(const bf16x8*)(xaD + mj * 16 * XP + kt * 32);
                    acc[mj][0] = __builtin_amdgcn_mfma_f32_16x16x32_bf16(a, b0, acc[mj][0], 0, 0, 0);
                    acc[mj][1] = __builtin_amdgcn_mfma_f32_16x16x32_bf16(a, b1, acc[mj][1], 0, 0, 0);
                }
            }
            // pointwise LSTM: 4-lane gate exchange, lane owns agent-subrow i==go
            #pragma unroll
            for (int mj = 0; mj < 4; ++mj) {
                const int a = mj * 16 + q4 * 4 + go;
                const bool act = sh_act[a] != 0;
                #pragma unroll
                for (int s = 0; s < 2; ++s) {
                    const float z0 = acc[mj][s][0] + bs[s];
                    const float z1 = acc[mj][s][1] + bs[s];
                    const float z2 = acc[mj][s][2] + bs[s];
                    const float z3 = acc[mj][s][3] + bs[s];
                    const float s0 = sel4(z0, z1, z2, z3, go);
                    const float s1 = sel4(z0, z1, z2, z3, go ^ 1);
                    const float s2 = sel4(z0, z1, z2, z3, go ^ 2);
                    const float s3 = sel4(z0, z1, z2, z3, go ^ 3);
                    const float t1 = __shfl_xor(s1, 1, 64);
                    const float t2 = __shfl_xor(s2, 2, 64);
                    const float t3 = __shfl_xor(s3, 3, 64);
                    const float zi = sel4(s0, t1, t2, t3, go);
                    const float zf = sel4(s0, t1, t2, t3, go ^ 1);
                    const float zg = sel4(s0, t1, t2, t3, go ^ 2);
                    const float zo = sel4(s0, t1, t2, t3, go ^ 3);
                    const float cold = c_st[mj][s];
                    const float cn = sigmf(zf) * cold + sigmf(zi) * tanhf_fast(zg);
                    const float hn = sigmf(zo) * tanhf_fast(cn);
                    c_st[mj][s] = act ? cn : cold;
                    const float hold = bf2f(sh_X[a][128 + dimv[s]]);
                    hnew[mj][s] = act ? hn : hold;
                }
            }
        }
        __syncthreads();   // everyone done reading h region
        #pragma unroll
        for (int mj = 0; mj < 4; ++mj) {
            const int a = mj * 16 + q4 * 4 + go;
            sh_X[a][128 + dimv[0]] = f2bf(hnew[mj][0]);
            sh_X[a][128 + dimv[1]] = f2bf(hnew[mj][1]);
        }
        __syncthreads();
    }
}

extern "C" void kernel_launch(void* const* d_in, const int* in_sizes, int n_in,
                              void* d_out, int out_size, void* d_ws, size_t ws_size,
                              hipStream_t stream) {
    (void)in_sizes; (void)n_in; (void)out_size; (void)ws_size;
    unsigned short* wd = (unsigned short*)d_ws;            // 256 KiB
    unsigned short* wb = wd + 131072;                      //  64 KiB
    prep_weights<<<640, 256, 0, stream>>>(
        (const float*)d_in[9], (const float*)d_in[10], (const float*)d_in[7], wd, wb);
    social_lstm_mfma<<<16, NTHR, 0, stream>>>(
        (const float*)d_in[0],   // past_traj
        (const float*)d_in[1],   // past_traj_rel
        (const int*)  d_in[2],   // ts mask
        (const int*)  d_in[4],   // same_scene_mask
        (const float*)d_in[5],   // pos_W
        (const float*)d_in[6],   // pos_b
        (const float*)d_in[8],   // soc_b
        (const float*)d_in[11],  // bih
        (const float*)d_in[12],  // bhh
        (const float*)d_in[13],  // h0
        (const float*)d_in[14],  // c0
        (const float*)d_in[15],  // pred_W
        (const float*)d_in[16],  // pred_b
        wd, wb,
        (float*)d_out);
}